// Round 5
// baseline (5960.489 us; speedup 1.0000x reference)
//
#include <hip/hip_runtime.h>
#include <cstdint>
#include <cstddef>

// Problem constants
#define B_    16
#define N_    512
#define L_    2048
#define DIM_  768
#define M_    8
#define CE_   64
#define VOCAB_ 1024
#define H_    128
#define G4_   512   // 4*H
#define XDIM_ 128   // 2*CE

typedef __bf16 bf16x8 __attribute__((ext_vector_type(8)));
typedef float  f32x4  __attribute__((ext_vector_type(4)));

__device__ __forceinline__ unsigned short f2bf(float f) {
    unsigned u = __float_as_uint(f);
    u += 0x7fffu + ((u >> 16) & 1u);   // RNE
    return (unsigned short)(u >> 16);
}

// ---------------------------------------------------------------------------
// Generic fp32 tiled GEMM: C[M,N] = A[M,K] @ B + bias1 (+bias2)
//   TRANSB=false: B is [K,N] row-major.  TRANSB=true: B is [N,K] row-major (use B^T).
// 128x128 tile, BK=8, 256 threads, 8x8 per thread.
// ---------------------------------------------------------------------------
template<bool TRANSB>
__global__ __launch_bounds__(256) void gemm_f32(
    const float* __restrict__ A, const float* __restrict__ Bm,
    const float* __restrict__ bias1, const float* __restrict__ bias2,
    float* __restrict__ C, int M, int N, int K)
{
    __shared__ float As[8][128];
    __shared__ float Bs[8][128];
    const int t  = threadIdx.x;
    const int tx = t & 15, ty = t >> 4;
    const int m0 = blockIdx.y * 128, n0 = blockIdx.x * 128;
    const int arow = t >> 1, ahalf = (t & 1) * 4;

    float acc[8][8];
#pragma unroll
    for (int i = 0; i < 8; i++)
#pragma unroll
        for (int j = 0; j < 8; j++) acc[i][j] = 0.f;

    for (int k0 = 0; k0 < K; k0 += 8) {
        float4 av = *(const float4*)(A + (size_t)(m0 + arow) * K + k0 + ahalf);
        float4 bv;
        if (TRANSB) {
            bv = *(const float4*)(Bm + (size_t)(n0 + arow) * K + k0 + ahalf);
        } else {
            int kk = t >> 5, nn = (t & 31) * 4;
            bv = *(const float4*)(Bm + (size_t)(k0 + kk) * N + n0 + nn);
        }
        __syncthreads();   // previous iter's compute done before LDS overwrite
        As[ahalf + 0][arow] = av.x;
        As[ahalf + 1][arow] = av.y;
        As[ahalf + 2][arow] = av.z;
        As[ahalf + 3][arow] = av.w;
        if (TRANSB) {
            Bs[ahalf + 0][arow] = bv.x;
            Bs[ahalf + 1][arow] = bv.y;
            Bs[ahalf + 2][arow] = bv.z;
            Bs[ahalf + 3][arow] = bv.w;
        } else {
            int kk = t >> 5, nn = (t & 31) * 4;
            *(float4*)&Bs[kk][nn] = bv;
        }
        __syncthreads();
#pragma unroll
        for (int k = 0; k < 8; k++) {
            float a[8], bb[8];
            *(float4*)&a[0]  = *(const float4*)&As[k][ty * 8];
            *(float4*)&a[4]  = *(const float4*)&As[k][ty * 8 + 4];
            *(float4*)&bb[0] = *(const float4*)&Bs[k][tx * 8];
            *(float4*)&bb[4] = *(const float4*)&Bs[k][tx * 8 + 4];
#pragma unroll
            for (int i = 0; i < 8; i++)
#pragma unroll
                for (int j = 0; j < 8; j++)
                    acc[i][j] = fmaf(a[i], bb[j], acc[i][j]);
        }
    }

    float bia[8];
#pragma unroll
    for (int j = 0; j < 8; j++) {
        int gn = n0 + tx * 8 + j;
        bia[j] = bias1[gn] + (bias2 ? bias2[gn] : 0.f);
    }
#pragma unroll
    for (int i = 0; i < 8; i++) {
        size_t row = (size_t)(m0 + ty * 8 + i) * N + n0 + tx * 8;
#pragma unroll
        for (int j = 0; j < 8; j++)
            C[row + j] = acc[i][j] + bia[j];
    }
}

// ---------------------------------------------------------------------------
// Exclusive scan of word lengths per batch (N_=512 words, one block per batch)
// ---------------------------------------------------------------------------
__global__ __launch_bounds__(512) void scan_lens(const int* __restrict__ lens,
                                                 int* __restrict__ off)
{
    const int b = blockIdx.x, t = threadIdx.x;
    __shared__ int s[512];
    int v = lens[b * N_ + t];
    s[t] = v;
    __syncthreads();
    for (int d = 1; d < 512; d <<= 1) {
        int u = (t >= d) ? s[t - d] : 0;
        __syncthreads();
        s[t] += u;
        __syncthreads();
    }
    off[b * N_ + t] = s[t] - v;   // exclusive prefix
}

// ---------------------------------------------------------------------------
// dec_char gather: x[b,l,0:64] = char_emb[ids[b,l]]
// ---------------------------------------------------------------------------
__global__ __launch_bounds__(256) void char_gather(const int* __restrict__ ids,
                                                   const float* __restrict__ emb,
                                                   float* __restrict__ x)
{
    int g  = blockIdx.x * 4 + (threadIdx.x >> 6);   // (b,l) flat
    int cc = threadIdx.x & 63;
    int id = ids[g];
    x[(size_t)g * XDIM_ + cc] = emb[id * CE_ + cc];
}

// ---------------------------------------------------------------------------
// Ragged scatter: x[b, off+m, 64+c] = rep[b,n,m,c] for m < len, off+m < L
// ---------------------------------------------------------------------------
__global__ __launch_bounds__(512) void scatter_pad(const float* __restrict__ rep,
                                                   const int* __restrict__ lens,
                                                   const int* __restrict__ off,
                                                   float* __restrict__ x)
{
    int word = blockIdx.x;            // b*512 + n
    int b = word >> 9;
    int m  = threadIdx.x >> 6;
    int cc = threadIdx.x & 63;
    int len = lens[word];
    if (m < len) {
        int dst = off[word] + m;
        if (dst < L_) {
            x[((size_t)b * L_ + dst) * XDIM_ + CE_ + cc] =
                rep[((size_t)word * M_ + m) * CE_ + cc];
        }
    }
}

// ---------------------------------------------------------------------------
// LSTM recurrence. TWO batch elements per block (8 blocks, 1024 thr = 16
// waves: waves 0-7 run batch 2b, waves 8-15 run batch 2b+1, separate hbuf
// halves, identical control flow -> shared s_barrier is safe).
//
// R2 (measured 926 us): rcp activations, g-gate 2+2 MFMA split, gx folded
// into C-in, cvt_pk h->bf16, lgkm-only asm barrier.
// R3 post-mortem: clobberless-barrier + i/f/o split = 948 us (-2%) ->
// vmcnt-drain theory wrong ("memory" clobber never drained vmcnt; it's an
// IR fence only). Both edits reverted to the 926-us R2 body.
// R4 theory: step = 1085 cyc vs ~580 issue + ~430 serial chain -> ~500 cyc
// of UNHIDDEN latency because only 2 barrier-locked waves/SIMD (Occupancy
// 1.5%). Fix: co-schedule 2 independent recurrences per block -> 4 waves/
// SIMD; the second recurrence's MFMA/trans issue fills the first's
// dependency stalls (plain TLP, no ordering assumptions).
// ---------------------------------------------------------------------------
__global__ __launch_bounds__(1024) void lstm_rec(const float* __restrict__ gx,   // [B,L,512]
                                                 const float* __restrict__ Whh,  // [512,128]
                                                 float* __restrict__ hs)         // [B,L,128]
{
    const int tid_g = threadIdx.x;
    const int half  = tid_g >> 9;              // which of the 2 batches in this block
    const int tid   = tid_g & 511;             // thread id within the recurrence
    const int b     = blockIdx.x * 2 + half;
    const int wave  = tid >> 6, lane = tid & 63;
    const int quad  = lane >> 4, l15 = lane & 15;
    const int j     = wave * 16 + l15;         // hidden index owned by this lane

    __shared__ __align__(16) unsigned short hbuf[2][2][128];   // [half][pb][j]
    if (tid < 128) hbuf[half][0][tid] = 0;     // h_{-1} = 0 (bf16 zero bits)

    // B fragments: bfrag[q][kk] holds W_hh[q*128 + j][kk*32 + quad*8 + 0..7] (bf16)
    bf16x8 bfrag[4][4];
#pragma unroll
    for (int q = 0; q < 4; q++) {
        const float* wrow = Whh + (size_t)(q * 128 + j) * H_;
#pragma unroll
        for (int kk = 0; kk < 4; kk++) {
            int kb = kk * 32 + quad * 8;
            float4 w0 = *(const float4*)(wrow + kb);
            float4 w1 = *(const float4*)(wrow + kb + 4);
            union { unsigned short u[8]; bf16x8 v; } U;
            U.u[0] = f2bf(w0.x); U.u[1] = f2bf(w0.y); U.u[2] = f2bf(w0.z); U.u[3] = f2bf(w0.w);
            U.u[4] = f2bf(w1.x); U.u[5] = f2bf(w1.y); U.u[6] = f2bf(w1.z); U.u[7] = f2bf(w1.w);
            bfrag[q][kk] = U.v;
        }
    }

    // gx prefetch ring: depth 4, indices static after unroll.
    const float* gxb = gx + (size_t)b * L_ * G4_ + j;
    float pf[4][4];
#pragma unroll
    for (int u = 0; u < 4; u++)
#pragma unroll
        for (int q = 0; q < 4; q++)
            pf[u][q] = gxb[(size_t)u * G4_ + q * 128];

    float c = 0.f;
    float* hsb = hs + (size_t)b * L_ * H_;
    __syncthreads();   // full sync once (init hbuf visible); drains prefetch, ok

#define RCP_(x) __builtin_amdgcn_rcpf(x)
#define MFMA_(a, bb, cc) __builtin_amdgcn_mfma_f32_16x16x32_bf16(a, bb, cc, 0, 0, 0)

    for (int t0 = 0; t0 < L_; t0 += 4) {
#pragma unroll
        for (int u = 0; u < 4; u++) {
            const int t  = t0 + u;
            const int pb = t & 1;

            // A fragments (h broadcast across rows)
            bf16x8 a0 = *(const bf16x8*)&hbuf[half][pb][0 * 32 + quad * 8];
            bf16x8 a1 = *(const bf16x8*)&hbuf[half][pb][1 * 32 + quad * 8];
            bf16x8 a2 = *(const bf16x8*)&hbuf[half][pb][2 * 32 + quad * 8];
            bf16x8 a3 = *(const bf16x8*)&hbuf[half][pb][3 * 32 + quad * 8];

            // C-in reg0 carries the gx pre-activation (only reg0 is consumed)
            f32x4 accga = {pf[u][2], 0.f, 0.f, 0.f};   // g gate, chain a (kk0,kk2)
            f32x4 accgb = {0.f, 0.f, 0.f, 0.f};        // g gate, chain b (kk1,kk3)
            f32x4 acci  = {pf[u][0], 0.f, 0.f, 0.f};
            f32x4 accf  = {pf[u][1], 0.f, 0.f, 0.f};
            f32x4 acco  = {pf[u][3], 0.f, 0.f, 0.f};

            // refill this ring slot for t+4 (stays in flight across raw barrier)
            {
                int tn = t + 4; if (tn > L_ - 1) tn = L_ - 1;
#pragma unroll
                for (int q = 0; q < 4; q++) pf[u][q] = gxb[(size_t)tn * G4_ + q * 128];
            }

            // g first (two 2-deep chains -> earliest completion), then i, f, o
            accga = MFMA_(a0, bfrag[2][0], accga);
            accgb = MFMA_(a1, bfrag[2][1], accgb);
            acci  = MFMA_(a0, bfrag[0][0], acci);
            accf  = MFMA_(a0, bfrag[1][0], accf);
            acco  = MFMA_(a0, bfrag[3][0], acco);
            accga = MFMA_(a2, bfrag[2][2], accga);
            accgb = MFMA_(a3, bfrag[2][3], accgb);
            acci  = MFMA_(a1, bfrag[0][1], acci);
            accf  = MFMA_(a1, bfrag[1][1], accf);
            acco  = MFMA_(a1, bfrag[3][1], acco);
            acci  = MFMA_(a2, bfrag[0][2], acci);
            accf  = MFMA_(a2, bfrag[1][2], accf);
            acco  = MFMA_(a2, bfrag[3][2], acco);
            acci  = MFMA_(a3, bfrag[0][3], acci);
            accf  = MFMA_(a3, bfrag[1][3], accf);
            acco  = MFMA_(a3, bfrag[3][3], acco);

            // activations: raw v_rcp_f32 (no IEEE div sequence on the chain)
            float gg = accga[0] + accgb[0];
            float tg = 1.f - 2.f * RCP_(__expf(2.f * gg) + 1.f);
            float si = RCP_(1.f + __expf(-acci[0]));
            float sf = RCP_(1.f + __expf(-accf[0]));
            float so = RCP_(1.f + __expf(-acco[0]));
            c = sf * c + si * tg;
            float tc = 1.f - 2.f * RCP_(__expf(2.f * c) + 1.f);
            float h = so * tc;

            unsigned hr;
            asm("v_cvt_pk_bf16_f32 %0, %1, %2" : "=v"(hr) : "v"(h), "v"(h));
            if (quad == 0) {
                hbuf[half][pb ^ 1][j] = (unsigned short)hr;
                hsb[(size_t)t * H_ + j] = h;
            }
            // LDS-only drain + barrier: do NOT force vmcnt(0) like __syncthreads
            asm volatile("s_waitcnt lgkmcnt(0)\n\ts_barrier" ::: "memory");
        }
    }
#undef RCP_
#undef MFMA_
}

// ---------------------------------------------------------------------------
// Launch. Workspace layout (bytes):
//   rep : [0, 16 MiB)            8192 x 512 fp32
//   x   : [16 MiB, 32 MiB)       16 x 2048 x 128 fp32
//   hs  : [32 MiB, 48 MiB)       16 x 2048 x 128 fp32
//   off : [48 MiB, +32 KiB)      16 x 512 int
// gx (64 MiB) staged in d_out, consumed by lstm_rec before the final GEMM.
// ---------------------------------------------------------------------------
extern "C" void kernel_launch(void* const* d_in, const int* in_sizes, int n_in,
                              void* d_out, int out_size, void* d_ws, size_t ws_size,
                              hipStream_t stream)
{
    (void)in_sizes; (void)n_in; (void)out_size; (void)ws_size;
    const float* dec_hidden = (const float*)d_in[0];
    const int*   ids        = (const int*)d_in[1];
    const int*   lens       = (const int*)d_in[2];
    const float* char_emb   = (const float*)d_in[3];
    const float* W_proj     = (const float*)d_in[4];
    const float* b_proj     = (const float*)d_in[5];
    const float* W_ih       = (const float*)d_in[6];
    const float* W_hh       = (const float*)d_in[7];
    const float* b_ih       = (const float*)d_in[8];
    const float* b_hh       = (const float*)d_in[9];
    const float* W_pred     = (const float*)d_in[10];
    const float* b_pred     = (const float*)d_in[11];
    float* out = (float*)d_out;

    char* ws   = (char*)d_ws;
    float* rep = (float*)(ws);
    float* x   = (float*)(ws + (size_t)16 * 1024 * 1024);
    float* hs  = (float*)(ws + (size_t)32 * 1024 * 1024);
    int*   off = (int*)  (ws + (size_t)48 * 1024 * 1024);
    float* gx  = out;   // staged in output buffer, consumed before final GEMM

    // zero the x buffer (padded region must be zero where no chars land)
    hipMemsetAsync(x, 0, (size_t)B_ * L_ * XDIM_ * sizeof(float), stream);

    // 1) rep = dec_hidden @ W_proj + b_proj   [8192,768]x[768,512]
    gemm_f32<false><<<dim3(4, 64), 256, 0, stream>>>(
        dec_hidden, W_proj, b_proj, nullptr, rep, B_ * N_, 512, DIM_);

    // 2) per-batch exclusive scan of word lengths
    scan_lens<<<B_, 512, 0, stream>>>(lens, off);

    // 3) build x = concat(char_emb[ids], scatter(rep))
    char_gather<<<(B_ * L_) / 4, 256, 0, stream>>>(ids, char_emb, x);
    scatter_pad<<<B_ * N_, 512, 0, stream>>>(rep, lens, off, x);

    // 4) gx = x @ W_ih^T + b_ih + b_hh        [32768,128]x[512,128]^T
    gemm_f32<true><<<dim3(4, 256), 256, 0, stream>>>(
        x, W_ih, b_ih, b_hh, gx, B_ * L_, G4_, XDIM_);

    // 5) sequential LSTM (the critical path): 2 batches per block
    lstm_rec<<<B_ / 2, 1024, 0, stream>>>(gx, W_hh, hs);

    // 6) out = hs @ W_pred + b_pred           [32768,128]x[128,1024]
    gemm_f32<false><<<dim3(8, 256), 256, 0, stream>>>(
        hs, W_pred, b_pred, nullptr, out, B_ * L_, VOCAB_, H_);
}

// Round 6
// 1943.808 us; speedup vs baseline: 3.0664x; 3.0664x over previous
//
#include <hip/hip_runtime.h>
#include <cstdint>
#include <cstddef>

// Problem constants
#define B_    16
#define N_    512
#define L_    2048
#define DIM_  768
#define M_    8
#define CE_   64
#define VOCAB_ 1024
#define H_    128
#define G4_   512   // 4*H
#define XDIM_ 128   // 2*CE

typedef __bf16 bf16x8 __attribute__((ext_vector_type(8)));
typedef float  f32x4  __attribute__((ext_vector_type(4)));

__device__ __forceinline__ unsigned short f2bf(float f) {
    unsigned u = __float_as_uint(f);
    u += 0x7fffu + ((u >> 16) & 1u);   // RNE
    return (unsigned short)(u >> 16);
}

// ---------------------------------------------------------------------------
// Generic fp32 tiled GEMM: C[M,N] = A[M,K] @ B + bias1 (+bias2)
//   TRANSB=false: B is [K,N] row-major.  TRANSB=true: B is [N,K] row-major (use B^T).
// 128x128 tile, BK=8, 256 threads, 8x8 per thread.
// ---------------------------------------------------------------------------
template<bool TRANSB>
__global__ __launch_bounds__(256) void gemm_f32(
    const float* __restrict__ A, const float* __restrict__ Bm,
    const float* __restrict__ bias1, const float* __restrict__ bias2,
    float* __restrict__ C, int M, int N, int K)
{
    __shared__ float As[8][128];
    __shared__ float Bs[8][128];
    const int t  = threadIdx.x;
    const int tx = t & 15, ty = t >> 4;
    const int m0 = blockIdx.y * 128, n0 = blockIdx.x * 128;
    const int arow = t >> 1, ahalf = (t & 1) * 4;

    float acc[8][8];
#pragma unroll
    for (int i = 0; i < 8; i++)
#pragma unroll
        for (int j = 0; j < 8; j++) acc[i][j] = 0.f;

    for (int k0 = 0; k0 < K; k0 += 8) {
        float4 av = *(const float4*)(A + (size_t)(m0 + arow) * K + k0 + ahalf);
        float4 bv;
        if (TRANSB) {
            bv = *(const float4*)(Bm + (size_t)(n0 + arow) * K + k0 + ahalf);
        } else {
            int kk = t >> 5, nn = (t & 31) * 4;
            bv = *(const float4*)(Bm + (size_t)(k0 + kk) * N + n0 + nn);
        }
        __syncthreads();   // previous iter's compute done before LDS overwrite
        As[ahalf + 0][arow] = av.x;
        As[ahalf + 1][arow] = av.y;
        As[ahalf + 2][arow] = av.z;
        As[ahalf + 3][arow] = av.w;
        if (TRANSB) {
            Bs[ahalf + 0][arow] = bv.x;
            Bs[ahalf + 1][arow] = bv.y;
            Bs[ahalf + 2][arow] = bv.z;
            Bs[ahalf + 3][arow] = bv.w;
        } else {
            int kk = t >> 5, nn = (t & 31) * 4;
            *(float4*)&Bs[kk][nn] = bv;
        }
        __syncthreads();
#pragma unroll
        for (int k = 0; k < 8; k++) {
            float a[8], bb[8];
            *(float4*)&a[0]  = *(const float4*)&As[k][ty * 8];
            *(float4*)&a[4]  = *(const float4*)&As[k][ty * 8 + 4];
            *(float4*)&bb[0] = *(const float4*)&Bs[k][tx * 8];
            *(float4*)&bb[4] = *(const float4*)&Bs[k][tx * 8 + 4];
#pragma unroll
            for (int i = 0; i < 8; i++)
#pragma unroll
                for (int j = 0; j < 8; j++)
                    acc[i][j] = fmaf(a[i], bb[j], acc[i][j]);
        }
    }

    float bia[8];
#pragma unroll
    for (int j = 0; j < 8; j++) {
        int gn = n0 + tx * 8 + j;
        bia[j] = bias1[gn] + (bias2 ? bias2[gn] : 0.f);
    }
#pragma unroll
    for (int i = 0; i < 8; i++) {
        size_t row = (size_t)(m0 + ty * 8 + i) * N + n0 + tx * 8;
#pragma unroll
        for (int j = 0; j < 8; j++)
            C[row + j] = acc[i][j] + bia[j];
    }
}

// ---------------------------------------------------------------------------
// Exclusive scan of word lengths per batch (N_=512 words, one block per batch)
// ---------------------------------------------------------------------------
__global__ __launch_bounds__(512) void scan_lens(const int* __restrict__ lens,
                                                 int* __restrict__ off)
{
    const int b = blockIdx.x, t = threadIdx.x;
    __shared__ int s[512];
    int v = lens[b * N_ + t];
    s[t] = v;
    __syncthreads();
    for (int d = 1; d < 512; d <<= 1) {
        int u = (t >= d) ? s[t - d] : 0;
        __syncthreads();
        s[t] += u;
        __syncthreads();
    }
    off[b * N_ + t] = s[t] - v;   // exclusive prefix
}

// ---------------------------------------------------------------------------
// dec_char gather: x[b,l,0:64] = char_emb[ids[b,l]]
// ---------------------------------------------------------------------------
__global__ __launch_bounds__(256) void char_gather(const int* __restrict__ ids,
                                                   const float* __restrict__ emb,
                                                   float* __restrict__ x)
{
    int g  = blockIdx.x * 4 + (threadIdx.x >> 6);   // (b,l) flat
    int cc = threadIdx.x & 63;
    int id = ids[g];
    x[(size_t)g * XDIM_ + cc] = emb[id * CE_ + cc];
}

// ---------------------------------------------------------------------------
// Ragged scatter: x[b, off+m, 64+c] = rep[b,n,m,c] for m < len, off+m < L
// ---------------------------------------------------------------------------
__global__ __launch_bounds__(512) void scatter_pad(const float* __restrict__ rep,
                                                   const int* __restrict__ lens,
                                                   const int* __restrict__ off,
                                                   float* __restrict__ x)
{
    int word = blockIdx.x;            // b*512 + n
    int b = word >> 9;
    int m  = threadIdx.x >> 6;
    int cc = threadIdx.x & 63;
    int len = lens[word];
    if (m < len) {
        int dst = off[word] + m;
        if (dst < L_) {
            x[((size_t)b * L_ + dst) * XDIM_ + CE_ + cc] =
                rep[((size_t)word * M_ + m) * CE_ + cc];
        }
    }
}

// ---------------------------------------------------------------------------
// LSTM recurrence. TWO batch elements per block (8 blocks, 1024 thr = 16
// waves: waves 0-7 run batch 2b, waves 8-15 run batch 2b+1, separate hbuf
// halves, identical control flow -> shared s_barrier is safe).
//
// R2 (measured 926 us, 512thr/1batch): rcp activations, g-gate 2+2 MFMA
// split, gx folded into C-in, cvt_pk h->bf16, lgkm-only asm barrier.
// R4 post-mortem: __launch_bounds__(1024) with no min-waves arg -> compiler
// targeted 2 blocks/CU = 64-VGPR cap; bfrag (64 regs of W_hh) spilled to
// scratch; L2-resident spill reloads serialized the step (1085 -> ~6400 cyc,
// 5481 us). TLP theory got NO verdict — experiment poisoned by the cap.
// R5 fix: __launch_bounds__(1024, 4) = exactly our 16 waves = 1 block/CU ->
// VGPR cap 128 (need ~120). Also pf ring depth 4 -> 2 (saves 8 VGPRs;
// distance 2 steps still covers HBM latency). Theory unchanged: 2
// independent recurrences per CU fill the ~565 cyc/step of unhidden
// latency that 2 barrier-locked waves/SIMD could not.
// ---------------------------------------------------------------------------
__global__ __launch_bounds__(1024, 4) void lstm_rec(const float* __restrict__ gx,   // [B,L,512]
                                                    const float* __restrict__ Whh,  // [512,128]
                                                    float* __restrict__ hs)         // [B,L,128]
{
    const int tid_g = threadIdx.x;
    const int half  = tid_g >> 9;              // which of the 2 batches in this block
    const int tid   = tid_g & 511;             // thread id within the recurrence
    const int b     = blockIdx.x * 2 + half;
    const int wave  = tid >> 6, lane = tid & 63;
    const int quad  = lane >> 4, l15 = lane & 15;
    const int j     = wave * 16 + l15;         // hidden index owned by this lane

    __shared__ __align__(16) unsigned short hbuf[2][2][128];   // [half][pb][j]
    if (tid < 128) hbuf[half][0][tid] = 0;     // h_{-1} = 0 (bf16 zero bits)

    // B fragments: bfrag[q][kk] holds W_hh[q*128 + j][kk*32 + quad*8 + 0..7] (bf16)
    bf16x8 bfrag[4][4];
#pragma unroll
    for (int q = 0; q < 4; q++) {
        const float* wrow = Whh + (size_t)(q * 128 + j) * H_;
#pragma unroll
        for (int kk = 0; kk < 4; kk++) {
            int kb = kk * 32 + quad * 8;
            float4 w0 = *(const float4*)(wrow + kb);
            float4 w1 = *(const float4*)(wrow + kb + 4);
            union { unsigned short u[8]; bf16x8 v; } U;
            U.u[0] = f2bf(w0.x); U.u[1] = f2bf(w0.y); U.u[2] = f2bf(w0.z); U.u[3] = f2bf(w0.w);
            U.u[4] = f2bf(w1.x); U.u[5] = f2bf(w1.y); U.u[6] = f2bf(w1.z); U.u[7] = f2bf(w1.w);
            bfrag[q][kk] = U.v;
        }
    }

    // gx prefetch ring: depth 2, indices static after unroll.
    const float* gxb = gx + (size_t)b * L_ * G4_ + j;
    float pf[2][4];
#pragma unroll
    for (int u = 0; u < 2; u++)
#pragma unroll
        for (int q = 0; q < 4; q++)
            pf[u][q] = gxb[(size_t)u * G4_ + q * 128];

    float c = 0.f;
    float* hsb = hs + (size_t)b * L_ * H_;
    __syncthreads();   // full sync once (init hbuf visible); drains prefetch, ok

#define RCP_(x) __builtin_amdgcn_rcpf(x)
#define MFMA_(a, bb, cc) __builtin_amdgcn_mfma_f32_16x16x32_bf16(a, bb, cc, 0, 0, 0)

    for (int t0 = 0; t0 < L_; t0 += 2) {
#pragma unroll
        for (int u = 0; u < 2; u++) {
            const int t  = t0 + u;
            const int pb = t & 1;

            // A fragments (h broadcast across rows)
            bf16x8 a0 = *(const bf16x8*)&hbuf[half][pb][0 * 32 + quad * 8];
            bf16x8 a1 = *(const bf16x8*)&hbuf[half][pb][1 * 32 + quad * 8];
            bf16x8 a2 = *(const bf16x8*)&hbuf[half][pb][2 * 32 + quad * 8];
            bf16x8 a3 = *(const bf16x8*)&hbuf[half][pb][3 * 32 + quad * 8];

            // C-in reg0 carries the gx pre-activation (only reg0 is consumed)
            f32x4 accga = {pf[u][2], 0.f, 0.f, 0.f};   // g gate, chain a (kk0,kk2)
            f32x4 accgb = {0.f, 0.f, 0.f, 0.f};        // g gate, chain b (kk1,kk3)
            f32x4 acci  = {pf[u][0], 0.f, 0.f, 0.f};
            f32x4 accf  = {pf[u][1], 0.f, 0.f, 0.f};
            f32x4 acco  = {pf[u][3], 0.f, 0.f, 0.f};

            // refill this ring slot for t+2 (stays in flight across raw barrier)
            {
                int tn = t + 2; if (tn > L_ - 1) tn = L_ - 1;
#pragma unroll
                for (int q = 0; q < 4; q++) pf[u][q] = gxb[(size_t)tn * G4_ + q * 128];
            }

            // g first (two 2-deep chains -> earliest completion), then i, f, o
            accga = MFMA_(a0, bfrag[2][0], accga);
            accgb = MFMA_(a1, bfrag[2][1], accgb);
            acci  = MFMA_(a0, bfrag[0][0], acci);
            accf  = MFMA_(a0, bfrag[1][0], accf);
            acco  = MFMA_(a0, bfrag[3][0], acco);
            accga = MFMA_(a2, bfrag[2][2], accga);
            accgb = MFMA_(a3, bfrag[2][3], accgb);
            acci  = MFMA_(a1, bfrag[0][1], acci);
            accf  = MFMA_(a1, bfrag[1][1], accf);
            acco  = MFMA_(a1, bfrag[3][1], acco);
            acci  = MFMA_(a2, bfrag[0][2], acci);
            accf  = MFMA_(a2, bfrag[1][2], accf);
            acco  = MFMA_(a2, bfrag[3][2], acco);
            acci  = MFMA_(a3, bfrag[0][3], acci);
            accf  = MFMA_(a3, bfrag[1][3], accf);
            acco  = MFMA_(a3, bfrag[3][3], acco);

            // activations: raw v_rcp_f32 (no IEEE div sequence on the chain)
            float gg = accga[0] + accgb[0];
            float tg = 1.f - 2.f * RCP_(__expf(2.f * gg) + 1.f);
            float si = RCP_(1.f + __expf(-acci[0]));
            float sf = RCP_(1.f + __expf(-accf[0]));
            float so = RCP_(1.f + __expf(-acco[0]));
            c = sf * c + si * tg;
            float tc = 1.f - 2.f * RCP_(__expf(2.f * c) + 1.f);
            float h = so * tc;

            unsigned hr;
            asm("v_cvt_pk_bf16_f32 %0, %1, %2" : "=v"(hr) : "v"(h), "v"(h));
            if (quad == 0) {
                hbuf[half][pb ^ 1][j] = (unsigned short)hr;
                hsb[(size_t)t * H_ + j] = h;
            }
            // LDS-only drain + barrier: do NOT force vmcnt(0) like __syncthreads
            asm volatile("s_waitcnt lgkmcnt(0)\n\ts_barrier" ::: "memory");
        }
    }
#undef RCP_
#undef MFMA_
}

// ---------------------------------------------------------------------------
// Launch. Workspace layout (bytes):
//   rep : [0, 16 MiB)            8192 x 512 fp32
//   x   : [16 MiB, 32 MiB)       16 x 2048 x 128 fp32
//   hs  : [32 MiB, 48 MiB)       16 x 2048 x 128 fp32
//   off : [48 MiB, +32 KiB)      16 x 512 int
// gx (64 MiB) staged in d_out, consumed by lstm_rec before the final GEMM.
// ---------------------------------------------------------------------------
extern "C" void kernel_launch(void* const* d_in, const int* in_sizes, int n_in,
                              void* d_out, int out_size, void* d_ws, size_t ws_size,
                              hipStream_t stream)
{
    (void)in_sizes; (void)n_in; (void)out_size; (void)ws_size;
    const float* dec_hidden = (const float*)d_in[0];
    const int*   ids        = (const int*)d_in[1];
    const int*   lens       = (const int*)d_in[2];
    const float* char_emb   = (const float*)d_in[3];
    const float* W_proj     = (const float*)d_in[4];
    const float* b_proj     = (const float*)d_in[5];
    const float* W_ih       = (const float*)d_in[6];
    const float* W_hh       = (const float*)d_in[7];
    const float* b_ih       = (const float*)d_in[8];
    const float* b_hh       = (const float*)d_in[9];
    const float* W_pred     = (const float*)d_in[10];
    const float* b_pred     = (const float*)d_in[11];
    float* out = (float*)d_out;

    char* ws   = (char*)d_ws;
    float* rep = (float*)(ws);
    float* x   = (float*)(ws + (size_t)16 * 1024 * 1024);
    float* hs  = (float*)(ws + (size_t)32 * 1024 * 1024);
    int*   off = (int*)  (ws + (size_t)48 * 1024 * 1024);
    float* gx  = out;   // staged in output buffer, consumed before final GEMM

    // zero the x buffer (padded region must be zero where no chars land)
    hipMemsetAsync(x, 0, (size_t)B_ * L_ * XDIM_ * sizeof(float), stream);

    // 1) rep = dec_hidden @ W_proj + b_proj   [8192,768]x[768,512]
    gemm_f32<false><<<dim3(4, 64), 256, 0, stream>>>(
        dec_hidden, W_proj, b_proj, nullptr, rep, B_ * N_, 512, DIM_);

    // 2) per-batch exclusive scan of word lengths
    scan_lens<<<B_, 512, 0, stream>>>(lens, off);

    // 3) build x = concat(char_emb[ids], scatter(rep))
    char_gather<<<(B_ * L_) / 4, 256, 0, stream>>>(ids, char_emb, x);
    scatter_pad<<<B_ * N_, 512, 0, stream>>>(rep, lens, off, x);

    // 4) gx = x @ W_ih^T + b_ih + b_hh        [32768,128]x[512,128]^T
    gemm_f32<true><<<dim3(4, 256), 256, 0, stream>>>(
        x, W_ih, b_ih, b_hh, gx, B_ * L_, G4_, XDIM_);

    // 5) sequential LSTM (the critical path): 2 batches per block
    lstm_rec<<<B_ / 2, 1024, 0, stream>>>(gx, W_hh, hs);

    // 6) out = hs @ W_pred + b_pred           [32768,128]x[128,1024]
    gemm_f32<false><<<dim3(8, 256), 256, 0, stream>>>(
        hs, W_pred, b_pred, nullptr, out, B_ * L_, VOCAB_, H_);
}

// Round 7
// 1366.333 us; speedup vs baseline: 4.3624x; 1.4226x over previous
//
#include <hip/hip_runtime.h>
#include <cstdint>
#include <cstddef>

// Problem constants
#define B_    16
#define N_    512
#define L_    2048
#define DIM_  768
#define M_    8
#define CE_   64
#define VOCAB_ 1024
#define H_    128
#define G4_   512   // 4*H
#define XDIM_ 128   // 2*CE

typedef __bf16 bf16x8 __attribute__((ext_vector_type(8)));
typedef float  f32x4  __attribute__((ext_vector_type(4)));

__device__ __forceinline__ unsigned short f2bf(float f) {
    unsigned u = __float_as_uint(f);
    u += 0x7fffu + ((u >> 16) & 1u);   // RNE
    return (unsigned short)(u >> 16);
}

// ---------------------------------------------------------------------------
// Generic fp32 tiled GEMM: C[M,N] = A[M,K] @ B + bias1 (+bias2)
//   TRANSB=false: B is [K,N] row-major.  TRANSB=true: B is [N,K] row-major.
// 128x128 tile, BK=8, 256 threads, 8x8 per thread.
// R6: double-buffered LDS -> ONE __syncthreads per K-step (was 2) and the
// next tile's global loads are issued BEFORE the compute phase so the FMA
// block hides their latency.
// ---------------------------------------------------------------------------
template<bool TRANSB>
__global__ __launch_bounds__(256) void gemm_f32(
    const float* __restrict__ A, const float* __restrict__ Bm,
    const float* __restrict__ bias1, const float* __restrict__ bias2,
    float* __restrict__ C, int M, int N, int K)
{
    __shared__ float As[2][8][128];
    __shared__ float Bs[2][8][128];
    const int t  = threadIdx.x;
    const int tx = t & 15, ty = t >> 4;
    const int m0 = blockIdx.y * 128, n0 = blockIdx.x * 128;
    const int arow = t >> 1, ahalf = (t & 1) * 4;
    const int bk = t >> 5, bn = (t & 31) * 4;

    float acc[8][8];
#pragma unroll
    for (int i = 0; i < 8; i++)
#pragma unroll
        for (int j = 0; j < 8; j++) acc[i][j] = 0.f;

    // preload + stage tile 0
    {
        float4 av = *(const float4*)(A + (size_t)(m0 + arow) * K + ahalf);
        float4 bv;
        if (TRANSB) bv = *(const float4*)(Bm + (size_t)(n0 + arow) * K + ahalf);
        else        bv = *(const float4*)(Bm + (size_t)bk * N + n0 + bn);
        As[0][ahalf + 0][arow] = av.x;
        As[0][ahalf + 1][arow] = av.y;
        As[0][ahalf + 2][arow] = av.z;
        As[0][ahalf + 3][arow] = av.w;
        if (TRANSB) {
            Bs[0][ahalf + 0][arow] = bv.x;
            Bs[0][ahalf + 1][arow] = bv.y;
            Bs[0][ahalf + 2][arow] = bv.z;
            Bs[0][ahalf + 3][arow] = bv.w;
        } else {
            *(float4*)&Bs[0][bk][bn] = bv;
        }
    }
    __syncthreads();

    int cur = 0;
    for (int k0 = 0; k0 < K; k0 += 8) {
        const bool more = (k0 + 8 < K);
        float4 av, bv;
        if (more) {   // issue next-tile loads BEFORE compute (latency hidden)
            av = *(const float4*)(A + (size_t)(m0 + arow) * K + (k0 + 8) + ahalf);
            if (TRANSB) bv = *(const float4*)(Bm + (size_t)(n0 + arow) * K + (k0 + 8) + ahalf);
            else        bv = *(const float4*)(Bm + (size_t)(k0 + 8 + bk) * N + n0 + bn);
        }
#pragma unroll
        for (int k = 0; k < 8; k++) {
            float a[8], bb[8];
            *(float4*)&a[0]  = *(const float4*)&As[cur][k][ty * 8];
            *(float4*)&a[4]  = *(const float4*)&As[cur][k][ty * 8 + 4];
            *(float4*)&bb[0] = *(const float4*)&Bs[cur][k][tx * 8];
            *(float4*)&bb[4] = *(const float4*)&Bs[cur][k][tx * 8 + 4];
#pragma unroll
            for (int i = 0; i < 8; i++)
#pragma unroll
                for (int j = 0; j < 8; j++)
                    acc[i][j] = fmaf(a[i], bb[j], acc[i][j]);
        }
        if (more) {   // stage into the buffer nobody is reading
            const int nxt = cur ^ 1;
            As[nxt][ahalf + 0][arow] = av.x;
            As[nxt][ahalf + 1][arow] = av.y;
            As[nxt][ahalf + 2][arow] = av.z;
            As[nxt][ahalf + 3][arow] = av.w;
            if (TRANSB) {
                Bs[nxt][ahalf + 0][arow] = bv.x;
                Bs[nxt][ahalf + 1][arow] = bv.y;
                Bs[nxt][ahalf + 2][arow] = bv.z;
                Bs[nxt][ahalf + 3][arow] = bv.w;
            } else {
                *(float4*)&Bs[nxt][bk][bn] = bv;
            }
        }
        __syncthreads();   // writes to nxt visible; reads of cur done
        cur ^= 1;
    }

    float bia[8];
#pragma unroll
    for (int j = 0; j < 8; j++) {
        int gn = n0 + tx * 8 + j;
        bia[j] = bias1[gn] + (bias2 ? bias2[gn] : 0.f);
    }
#pragma unroll
    for (int i = 0; i < 8; i++) {
        size_t row = (size_t)(m0 + ty * 8 + i) * N + n0 + tx * 8;
#pragma unroll
        for (int j = 0; j < 8; j++)
            C[row + j] = acc[i][j] + bia[j];
    }
}

// ---------------------------------------------------------------------------
// Exclusive scan of word lengths per batch (N_=512 words, one block per batch)
// ---------------------------------------------------------------------------
__global__ __launch_bounds__(512) void scan_lens(const int* __restrict__ lens,
                                                 int* __restrict__ off)
{
    const int b = blockIdx.x, t = threadIdx.x;
    __shared__ int s[512];
    int v = lens[b * N_ + t];
    s[t] = v;
    __syncthreads();
    for (int d = 1; d < 512; d <<= 1) {
        int u = (t >= d) ? s[t - d] : 0;
        __syncthreads();
        s[t] += u;
        __syncthreads();
    }
    off[b * N_ + t] = s[t] - v;   // exclusive prefix
}

// ---------------------------------------------------------------------------
// dec_char gather + zero-fill: x[b,l,0:64] = char_emb[ids[b,l]] (float4),
// x[b,l,64:128] = 0. Replaces the 16 MB memset (scatter_pad runs after and
// overwrites the populated subset of the pad region, same stream order).
// ---------------------------------------------------------------------------
__global__ __launch_bounds__(256) void char_gather(const int* __restrict__ ids,
                                                   const float* __restrict__ emb,
                                                   float* __restrict__ x)
{
    int g   = blockIdx.x * 8 + (threadIdx.x >> 5);   // (b,l) flat, 8 per block
    int l32 = threadIdx.x & 31;
    int id  = ids[g];
    float4 v;
    if (l32 < 16) v = *(const float4*)(emb + (size_t)id * CE_ + l32 * 4);
    else          v = make_float4(0.f, 0.f, 0.f, 0.f);
    *(float4*)(x + (size_t)g * XDIM_ + l32 * 4) = v;
}

// ---------------------------------------------------------------------------
// Ragged scatter: x[b, off+m, 64+c] = rep[b,n,m,c] for m < len, off+m < L
// ---------------------------------------------------------------------------
__global__ __launch_bounds__(512) void scatter_pad(const float* __restrict__ rep,
                                                   const int* __restrict__ lens,
                                                   const int* __restrict__ off,
                                                   float* __restrict__ x)
{
    int word = blockIdx.x;            // b*512 + n
    int b = word >> 9;
    int m  = threadIdx.x >> 6;
    int cc = threadIdx.x & 63;
    int len = lens[word];
    if (m < len) {
        int dst = off[word] + m;
        if (dst < L_) {
            x[((size_t)b * L_ + dst) * XDIM_ + CE_ + cc] =
                rep[((size_t)word * M_ + m) * CE_ + cc];
        }
    }
}

// ---------------------------------------------------------------------------
// LSTM recurrence — EXACT R2 body (measured 926 us). One block per batch
// (16 blocks, 512 thr = 8 waves). g = gx[b,t,:] + W_hh @ h via bf16 MFMA
// 16x16x32, h broadcast in A-rows, W_hh in registers as B-fragments.
//
// R4/R5 post-mortem: 1024-thr co-scheduling capped VGPR at 64 (16-wave
// blocks -> 128 unified budget) AND the shared s_barrier phase-locks the
// two recurrences (no anti-phase TLP possible; CDNA has no named barriers).
// Direction abandoned; this is the verified-fastest structure.
// ---------------------------------------------------------------------------
__global__ __launch_bounds__(512) void lstm_rec(const float* __restrict__ gx,   // [B,L,512]
                                                const float* __restrict__ Whh,  // [512,128]
                                                float* __restrict__ hs)         // [B,L,128]
{
    const int b    = blockIdx.x;
    const int tid  = threadIdx.x;
    const int wave = tid >> 6, lane = tid & 63;
    const int quad = lane >> 4, l15 = lane & 15;
    const int j    = wave * 16 + l15;          // hidden index owned by this lane

    __shared__ __align__(16) unsigned short hbuf[2][128];
    if (tid < 128) hbuf[0][tid] = 0;           // h_{-1} = 0 (bf16 zero bits)

    // B fragments: bfrag[q][kk] holds W_hh[q*128 + j][kk*32 + quad*8 + 0..7] (bf16)
    bf16x8 bfrag[4][4];
#pragma unroll
    for (int q = 0; q < 4; q++) {
        const float* wrow = Whh + (size_t)(q * 128 + j) * H_;
#pragma unroll
        for (int kk = 0; kk < 4; kk++) {
            int kb = kk * 32 + quad * 8;
            float4 w0 = *(const float4*)(wrow + kb);
            float4 w1 = *(const float4*)(wrow + kb + 4);
            union { unsigned short u[8]; bf16x8 v; } U;
            U.u[0] = f2bf(w0.x); U.u[1] = f2bf(w0.y); U.u[2] = f2bf(w0.z); U.u[3] = f2bf(w0.w);
            U.u[4] = f2bf(w1.x); U.u[5] = f2bf(w1.y); U.u[6] = f2bf(w1.z); U.u[7] = f2bf(w1.w);
            bfrag[q][kk] = U.v;
        }
    }

    // gx prefetch ring: depth 4, indices static after unroll.
    const float* gxb = gx + (size_t)b * L_ * G4_ + j;
    float pf[4][4];
#pragma unroll
    for (int u = 0; u < 4; u++)
#pragma unroll
        for (int q = 0; q < 4; q++)
            pf[u][q] = gxb[(size_t)u * G4_ + q * 128];

    float c = 0.f;
    float* hsb = hs + (size_t)b * L_ * H_;
    __syncthreads();   // full sync once (init hbuf visible); drains prefetch, ok

#define RCP_(x) __builtin_amdgcn_rcpf(x)
#define MFMA_(a, bb, cc) __builtin_amdgcn_mfma_f32_16x16x32_bf16(a, bb, cc, 0, 0, 0)

    for (int t0 = 0; t0 < L_; t0 += 4) {
#pragma unroll
        for (int u = 0; u < 4; u++) {
            const int t  = t0 + u;
            const int pb = t & 1;

            // A fragments (h broadcast across rows)
            bf16x8 a0 = *(const bf16x8*)&hbuf[pb][0 * 32 + quad * 8];
            bf16x8 a1 = *(const bf16x8*)&hbuf[pb][1 * 32 + quad * 8];
            bf16x8 a2 = *(const bf16x8*)&hbuf[pb][2 * 32 + quad * 8];
            bf16x8 a3 = *(const bf16x8*)&hbuf[pb][3 * 32 + quad * 8];

            // C-in reg0 carries the gx pre-activation (only reg0 is consumed)
            f32x4 accga = {pf[u][2], 0.f, 0.f, 0.f};   // g gate, chain a (kk0,kk2)
            f32x4 accgb = {0.f, 0.f, 0.f, 0.f};        // g gate, chain b (kk1,kk3)
            f32x4 acci  = {pf[u][0], 0.f, 0.f, 0.f};
            f32x4 accf  = {pf[u][1], 0.f, 0.f, 0.f};
            f32x4 acco  = {pf[u][3], 0.f, 0.f, 0.f};

            // refill this ring slot for t+4 (stays in flight across raw barrier)
            {
                int tn = t + 4; if (tn > L_ - 1) tn = L_ - 1;
#pragma unroll
                for (int q = 0; q < 4; q++) pf[u][q] = gxb[(size_t)tn * G4_ + q * 128];
            }

            // g first (two 2-deep chains -> earliest completion), then i, f, o
            accga = MFMA_(a0, bfrag[2][0], accga);
            accgb = MFMA_(a1, bfrag[2][1], accgb);
            acci  = MFMA_(a0, bfrag[0][0], acci);
            accf  = MFMA_(a0, bfrag[1][0], accf);
            acco  = MFMA_(a0, bfrag[3][0], acco);
            accga = MFMA_(a2, bfrag[2][2], accga);
            accgb = MFMA_(a3, bfrag[2][3], accgb);
            acci  = MFMA_(a1, bfrag[0][1], acci);
            accf  = MFMA_(a1, bfrag[1][1], accf);
            acco  = MFMA_(a1, bfrag[3][1], acco);
            acci  = MFMA_(a2, bfrag[0][2], acci);
            accf  = MFMA_(a2, bfrag[1][2], accf);
            acco  = MFMA_(a2, bfrag[3][2], acco);
            acci  = MFMA_(a3, bfrag[0][3], acci);
            accf  = MFMA_(a3, bfrag[1][3], accf);
            acco  = MFMA_(a3, bfrag[3][3], acco);

            // activations: raw v_rcp_f32 (no IEEE div sequence on the chain)
            float gg = accga[0] + accgb[0];
            float tg = 1.f - 2.f * RCP_(__expf(2.f * gg) + 1.f);
            float si = RCP_(1.f + __expf(-acci[0]));
            float sf = RCP_(1.f + __expf(-accf[0]));
            float so = RCP_(1.f + __expf(-acco[0]));
            c = sf * c + si * tg;
            float tc = 1.f - 2.f * RCP_(__expf(2.f * c) + 1.f);
            float h = so * tc;

            unsigned hr;
            asm("v_cvt_pk_bf16_f32 %0, %1, %2" : "=v"(hr) : "v"(h), "v"(h));
            if (quad == 0) {
                hbuf[pb ^ 1][j] = (unsigned short)hr;
                hsb[(size_t)t * H_ + j] = h;
            }
            // LDS-only drain + barrier: do NOT force vmcnt(0) like __syncthreads
            asm volatile("s_waitcnt lgkmcnt(0)\n\ts_barrier" ::: "memory");
        }
    }
#undef RCP_
#undef MFMA_
}

// ---------------------------------------------------------------------------
// Launch. Workspace layout (bytes):
//   rep : [0, 16 MiB)            8192 x 512 fp32
//   x   : [16 MiB, 32 MiB)       16 x 2048 x 128 fp32
//   hs  : [32 MiB, 48 MiB)       16 x 2048 x 128 fp32
//   off : [48 MiB, +32 KiB)      16 x 512 int
// gx (64 MiB) staged in d_out, consumed by lstm_rec before the final GEMM.
// ---------------------------------------------------------------------------
extern "C" void kernel_launch(void* const* d_in, const int* in_sizes, int n_in,
                              void* d_out, int out_size, void* d_ws, size_t ws_size,
                              hipStream_t stream)
{
    (void)in_sizes; (void)n_in; (void)out_size; (void)ws_size;
    const float* dec_hidden = (const float*)d_in[0];
    const int*   ids        = (const int*)d_in[1];
    const int*   lens       = (const int*)d_in[2];
    const float* char_emb   = (const float*)d_in[3];
    const float* W_proj     = (const float*)d_in[4];
    const float* b_proj     = (const float*)d_in[5];
    const float* W_ih       = (const float*)d_in[6];
    const float* W_hh       = (const float*)d_in[7];
    const float* b_ih       = (const float*)d_in[8];
    const float* b_hh       = (const float*)d_in[9];
    const float* W_pred     = (const float*)d_in[10];
    const float* b_pred     = (const float*)d_in[11];
    float* out = (float*)d_out;

    char* ws   = (char*)d_ws;
    float* rep = (float*)(ws);
    float* x   = (float*)(ws + (size_t)16 * 1024 * 1024);
    float* hs  = (float*)(ws + (size_t)32 * 1024 * 1024);
    int*   off = (int*)  (ws + (size_t)48 * 1024 * 1024);
    float* gx  = out;   // staged in output buffer, consumed before final GEMM

    // 1) rep = dec_hidden @ W_proj + b_proj   [8192,768]x[768,512]
    gemm_f32<false><<<dim3(4, 64), 256, 0, stream>>>(
        dec_hidden, W_proj, b_proj, nullptr, rep, B_ * N_, 512, DIM_);

    // 2) per-batch exclusive scan of word lengths
    scan_lens<<<B_, 512, 0, stream>>>(lens, off);

    // 3) build x = concat(char_emb[ids], 0-pad) then scatter rep into the pad
    //    (char_gather zero-fills x[...,64:128] -> no memset dispatch needed)
    char_gather<<<(B_ * L_) / 8, 256, 0, stream>>>(ids, char_emb, x);
    scatter_pad<<<B_ * N_, 512, 0, stream>>>(rep, lens, off, x);

    // 4) gx = x @ W_ih^T + b_ih + b_hh        [32768,128]x[512,128]^T
    gemm_f32<true><<<dim3(4, 256), 256, 0, stream>>>(
        x, W_ih, b_ih, b_hh, gx, B_ * L_, G4_, XDIM_);

    // 5) sequential LSTM (the critical path)
    lstm_rec<<<B_, 512, 0, stream>>>(gx, W_hh, hs);

    // 6) out = hs @ W_pred + b_pred           [32768,128]x[128,1024]
    gemm_f32<false><<<dim3(8, 256), 256, 0, stream>>>(
        hs, W_pred, b_pred, nullptr, out, B_ * L_, VOCAB_, H_);
}